// Round 1
// baseline (293.135 us; speedup 1.0000x reference)
//
#include <hip/hip_runtime.h>

typedef __attribute__((ext_vector_type(8))) short bf16x8;
typedef __attribute__((ext_vector_type(4))) float f32x4;

#define EPS 1e-5f

__device__ inline unsigned short f2bf(float x) {
  unsigned int u = __builtin_bit_cast(unsigned int, x);
  unsigned int r = (u + 0x7FFFu + ((u >> 16) & 1u)) >> 16;
  return (unsigned short)r;
}

// ---------------- prep: fold BN, pre-swizzle W1/W2 into MFMA fragment order ----------------
// ws layout: w1f bf16 [73728 B] | w2f bf16 [16384 B] | sc f32[384] (s1[128] c1[128] s2[64] c2[64])
__global__ void prep_kernel(const float* __restrict__ W1, const float* __restrict__ W2,
                            const float* __restrict__ b1, const float* __restrict__ g1,
                            const float* __restrict__ be1, const float* __restrict__ m1,
                            const float* __restrict__ v1,
                            const float* __restrict__ b2, const float* __restrict__ g2,
                            const float* __restrict__ be2, const float* __restrict__ m2,
                            const float* __restrict__ v2,
                            unsigned short* __restrict__ w1f, unsigned short* __restrict__ w2f,
                            float* __restrict__ sc) {
  int t = blockIdx.x * 256 + threadIdx.x;
  if (t < 36864) {
    // w1f[((kb*8+nb)*64 + lane)*8 + j] = W1[kb*32 + 8*(lane>>4) + j][nb*16 + (lane&15)]
    int j = t & 7, l = (t >> 3) & 63, f = t >> 9;
    int kb = f >> 3, nb = f & 7;
    int rk = kb * 32 + ((l >> 4) << 3) + j;
    int cn = (nb << 4) + (l & 15);
    w1f[t] = f2bf(W1[rk * 128 + cn]);
  } else if (t < 45056) {
    int o = t - 36864;
    int j = o & 7, l = (o >> 3) & 63, f = o >> 9;
    int kb = f >> 2, nb = f & 3;
    int rk = kb * 32 + ((l >> 4) << 3) + j;
    int cn = (nb << 4) + (l & 15);
    w2f[o] = f2bf(W2[rk * 64 + cn]);
  } else if (t < 45184) {
    int j = t - 45056;
    float s = g1[j] * rsqrtf(v1[j] + EPS);
    sc[j] = s;
    sc[128 + j] = (b1[j] - m1[j]) * s + be1[j];
  } else if (t < 45248) {
    int j = t - 45184;
    float s = g2[j] * rsqrtf(v2[j] + EPS);
    sc[256 + j] = s;
    sc[320 + j] = (b2[j] - m2[j]) * s + be2[j];
  }
}

// ---------------- fused main kernel ----------------
// LDS: [0,73728) W1 frags (persistent) | [73728,75776) SC: s1,c1,s2,c2,w3,b3 |
//      [75776,157696) dynamic region: A-tile [128 rows x 640 B] (during L1),
//        then x1 [128x256B] at +0, W2 frags at +32768, l3buf f32[256] at +49152
#define LDS_SC_OFF 73728
#define LDS_A_OFF 75776
#define LDS_TOTAL (75776 + 81920)

__global__ __launch_bounds__(256, 1) void fused_kernel(
    const float* __restrict__ z, const int* __restrict__ ei, const float* __restrict__ ctx,
    const unsigned short* __restrict__ w1f, const unsigned short* __restrict__ w2f,
    const float* __restrict__ sc, const float* __restrict__ w3, const float* __restrict__ b3,
    float* __restrict__ out, int E, int nblk) {
  extern __shared__ char lds[];
  char* W1B = lds;
  float* SC = (float*)(lds + LDS_SC_OFF);
  char* AR = lds + LDS_A_OFF;

  const int tid = threadIdx.x;
  {
    const f32x4* s = (const f32x4*)w1f;
    f32x4* d = (f32x4*)W1B;
#pragma unroll
    for (int i = 0; i < 18; i++) d[i * 256 + tid] = s[i * 256 + tid];
    if (tid < 128) {
      SC[tid] = sc[tid];
      SC[128 + tid] = sc[128 + tid];
    } else if (tid < 192) {
      int j = tid - 128;
      SC[256 + j] = sc[256 + j];
      SC[320 + j] = sc[320 + j];
      SC[384 + j] = w3[j];
    } else if (tid == 192) {
      SC[448] = b3[0];
    }
  }
  __syncthreads();

  const int lane = tid & 63, wave = tid >> 6;
  const int wr = wave >> 1, wc = wave & 1;
  const int g = lane >> 4, lq = lane & 15;

  for (int blk = blockIdx.x; blk < nblk; blk += gridDim.x) {
    const int base = blk << 7;

    // ---- stage A-tile: fused features [128 x 288] bf16, row stride 640 B, XOR-swizzled ----
    {
      const int r = tid >> 1, h = tid & 1;
      const int e = base + r;
      const int es = (e < E) ? e : 0;
      const int i0 = ei[es];
      const int i1 = ei[E + es];
      const f32x4* zs = (const f32x4*)(z + ((size_t)i0 * 64 + h * 32));
      const f32x4* zd = (const f32x4*)(z + ((size_t)i1 * 64 + h * 32));
      const f32x4* cx = (const f32x4*)(ctx + ((size_t)es * 32 + h * 16));
      f32x4 sv[8], dv[8], cv[4];
#pragma unroll
      for (int i = 0; i < 8; i++) { sv[i] = zs[i]; dv[i] = zd[i]; }
#pragma unroll
      for (int i = 0; i < 4; i++) cv[i] = cx[i];
      const int rswz = (r & 7) << 4;
      char* rowp = AR + r * 640;
#pragma unroll
      for (int c = 0; c < 4; c++) {
        bf16x8 ps, pd, pp, pa;
#pragma unroll
        for (int q = 0; q < 2; q++) {
          f32x4 a = sv[c * 2 + q], b = dv[c * 2 + q];
#pragma unroll
          for (int i = 0; i < 4; i++) {
            float fs = a[i], fd = b[i];
            ps[q * 4 + i] = (short)f2bf(fs);
            pd[q * 4 + i] = (short)f2bf(fd);
            pp[q * 4 + i] = (short)f2bf(fs * fd);
            pa[q * 4 + i] = (short)f2bf(fabsf(fs - fd));
          }
        }
        const int cb = h * 64 + c * 16;
        *(bf16x8*)(rowp + ((cb) ^ rswz)) = ps;
        *(bf16x8*)(rowp + ((128 + cb) ^ rswz)) = pd;
        *(bf16x8*)(rowp + ((256 + cb) ^ rswz)) = pp;
        *(bf16x8*)(rowp + ((384 + cb) ^ rswz)) = pa;
      }
      bf16x8 pc0, pc1;
#pragma unroll
      for (int i = 0; i < 4; i++) {
        pc0[i] = (short)f2bf(cv[0][i]);
        pc0[4 + i] = (short)f2bf(cv[1][i]);
        pc1[i] = (short)f2bf(cv[2][i]);
        pc1[4 + i] = (short)f2bf(cv[3][i]);
      }
      *(bf16x8*)(rowp + ((512 + h * 32) ^ rswz)) = pc0;
      *(bf16x8*)(rowp + ((512 + h * 32 + 16) ^ rswz)) = pc1;
    }
    __syncthreads();

    // ---- layer 1: A[128x288] @ W1[288x128], 4x4 acc frags per wave ----
    f32x4 acc[4][4];
#pragma unroll
    for (int mf = 0; mf < 4; mf++)
#pragma unroll
      for (int nf = 0; nf < 4; nf++) {
        f32x4 zv = {0.f, 0.f, 0.f, 0.f};
        acc[mf][nf] = zv;
      }
    const bf16x8* W1F = (const bf16x8*)W1B;
#pragma unroll
    for (int kb = 0; kb < 9; kb++) {
      bf16x8 a[4], b[4];
#pragma unroll
      for (int mf = 0; mf < 4; mf++) {
        int row = wr * 64 + mf * 16 + lq;
        a[mf] = *(const bf16x8*)(AR + row * 640 + ((kb * 64 + g * 16) ^ ((row & 7) << 4)));
      }
#pragma unroll
      for (int nf = 0; nf < 4; nf++) b[nf] = W1F[(kb * 8 + wc * 4 + nf) * 64 + lane];
#pragma unroll
      for (int mf = 0; mf < 4; mf++)
#pragma unroll
        for (int nf = 0; nf < 4; nf++)
          acc[mf][nf] = __builtin_amdgcn_mfma_f32_16x16x32_bf16(a[mf], b[nf], acc[mf][nf], 0, 0, 0);
    }
    __syncthreads();

    // ---- stage W2 frags into freed A region + write x1 (bn+relu, bf16, swizzled) ----
    {
      const f32x4* s = (const f32x4*)w2f;
      f32x4* d = (f32x4*)(AR + 32768);
#pragma unroll
      for (int i = 0; i < 4; i++) d[i * 256 + tid] = s[i * 256 + tid];
    }
#pragma unroll
    for (int nf = 0; nf < 4; nf++) {
      const int col = wc * 64 + nf * 16 + lq;
      const float s1v = SC[col], c1v = SC[128 + col];
#pragma unroll
      for (int mf = 0; mf < 4; mf++) {
#pragma unroll
        for (int j = 0; j < 4; j++) {
          int row = wr * 64 + mf * 16 + 4 * g + j;
          float v = fmaxf(acc[mf][nf][j] * s1v + c1v, 0.f);
          *(unsigned short*)(AR + row * 256 + ((col * 2) ^ ((row & 7) << 4))) = f2bf(v);
        }
      }
    }
    __syncthreads();

    // ---- layer 2: x1[128x128] @ W2[128x64], 4x2 acc frags per wave ----
    f32x4 acc2[4][2];
#pragma unroll
    for (int mf = 0; mf < 4; mf++)
#pragma unroll
      for (int nf = 0; nf < 2; nf++) {
        f32x4 zv = {0.f, 0.f, 0.f, 0.f};
        acc2[mf][nf] = zv;
      }
    const bf16x8* W2F = (const bf16x8*)(AR + 32768);
#pragma unroll
    for (int kb = 0; kb < 4; kb++) {
      bf16x8 a2[4], b2[2];
#pragma unroll
      for (int mf = 0; mf < 4; mf++) {
        int row = wr * 64 + mf * 16 + lq;
        a2[mf] = *(const bf16x8*)(AR + row * 256 + ((kb * 64 + g * 16) ^ ((row & 7) << 4)));
      }
#pragma unroll
      for (int nf = 0; nf < 2; nf++) b2[nf] = W2F[(kb * 4 + wc * 2 + nf) * 64 + lane];
#pragma unroll
      for (int mf = 0; mf < 4; mf++)
#pragma unroll
        for (int nf = 0; nf < 2; nf++)
          acc2[mf][nf] = __builtin_amdgcn_mfma_f32_16x16x32_bf16(a2[mf], b2[nf], acc2[mf][nf], 0, 0, 0);
    }

    // ---- layer 3: bn+relu then dot with w3, 16-lane shfl reduce ----
    float* l3 = (float*)(AR + 49152);
    const int colA = wc * 32 + lq, colB = colA + 16;
    const float s2A = SC[256 + colA], c2A = SC[320 + colA];
    const float s2B = SC[256 + colB], c2B = SC[320 + colB];
    const float w3A = SC[384 + colA], w3B = SC[384 + colB];
#pragma unroll
    for (int mf = 0; mf < 4; mf++) {
#pragma unroll
      for (int j = 0; j < 4; j++) {
        float vA = fmaxf(acc2[mf][0][j] * s2A + c2A, 0.f);
        float vB = fmaxf(acc2[mf][1][j] * s2B + c2B, 0.f);
        float p = vA * w3A + vB * w3B;
        p += __shfl_xor(p, 1);
        p += __shfl_xor(p, 2);
        p += __shfl_xor(p, 4);
        p += __shfl_xor(p, 8);
        if (lq == 0) l3[(wr * 64 + mf * 16 + 4 * g + j) * 2 + wc] = p;
      }
    }
    __syncthreads();
    if (tid < 128) {
      int e = base + tid;
      if (e < E) out[e] = l3[tid * 2] + l3[tid * 2 + 1] + SC[448];
    }
    __syncthreads();
  }
}

extern "C" void kernel_launch(void* const* d_in, const int* in_sizes, int n_in,
                              void* d_out, int out_size, void* d_ws, size_t ws_size,
                              hipStream_t stream) {
  const float* z = (const float*)d_in[0];
  const int* ei = (const int*)d_in[1];
  const float* ctx = (const float*)d_in[2];
  const float* W1 = (const float*)d_in[3];
  const float* b1 = (const float*)d_in[4];
  const float* g1 = (const float*)d_in[5];
  const float* be1 = (const float*)d_in[6];
  const float* m1 = (const float*)d_in[7];
  const float* v1 = (const float*)d_in[8];
  const float* W2 = (const float*)d_in[9];
  const float* b2 = (const float*)d_in[10];
  const float* g2 = (const float*)d_in[11];
  const float* be2 = (const float*)d_in[12];
  const float* m2 = (const float*)d_in[13];
  const float* v2 = (const float*)d_in[14];
  const float* W3 = (const float*)d_in[15];
  const float* b3 = (const float*)d_in[16];
  float* out = (float*)d_out;
  const int E = out_size;

  unsigned short* w1f = (unsigned short*)d_ws;
  unsigned short* w2f = (unsigned short*)((char*)d_ws + 73728);
  float* sc = (float*)((char*)d_ws + 90112);

  prep_kernel<<<177, 256, 0, stream>>>(W1, W2, b1, g1, be1, m1, v1,
                                       b2, g2, be2, m2, v2, w1f, w2f, sc);

  const int nblk = (E + 127) >> 7;
  (void)hipFuncSetAttribute((const void*)fused_kernel,
                            hipFuncAttributeMaxDynamicSharedMemorySize, LDS_TOTAL);
  fused_kernel<<<256, 256, LDS_TOTAL, stream>>>(z, ei, ctx, w1f, w2f, sc, W3, b3,
                                                out, E, nblk);
}

// Round 2
// 162.943 us; speedup vs baseline: 1.7990x; 1.7990x over previous
//
#include <hip/hip_runtime.h>
#include <hip/hip_bf16.h>

typedef __attribute__((ext_vector_type(8))) short bf16x8;
typedef __attribute__((ext_vector_type(4))) float f32x4;
typedef __attribute__((ext_vector_type(4))) unsigned int u32x4;
typedef __attribute__((ext_vector_type(2))) unsigned int u32x2;

#define EPS 1e-5f

__device__ inline unsigned short f2bf(float x) {
  unsigned int u = __builtin_bit_cast(unsigned int, x);
  unsigned int r = (u + 0x7FFFu + ((u >> 16) & 1u)) >> 16;
  return (unsigned short)r;
}

__device__ inline unsigned int pk2(float a, float b) {
  return (unsigned int)f2bf(a) | ((unsigned int)f2bf(b) << 16);
}

// ---------------- prep: fold BN, pre-swizzle W1/W2 into MFMA fragment order ----------------
// ws layout: w1f bf16 [73728 B] | w2f bf16 [16384 B] | sc f32[384]
__global__ void prep_kernel(const float* __restrict__ W1, const float* __restrict__ W2,
                            const float* __restrict__ b1, const float* __restrict__ g1,
                            const float* __restrict__ be1, const float* __restrict__ m1,
                            const float* __restrict__ v1,
                            const float* __restrict__ b2, const float* __restrict__ g2,
                            const float* __restrict__ be2, const float* __restrict__ m2,
                            const float* __restrict__ v2,
                            unsigned short* __restrict__ w1f, unsigned short* __restrict__ w2f,
                            float* __restrict__ sc) {
  int t = blockIdx.x * 256 + threadIdx.x;
  if (t < 36864) {
    int j = t & 7, l = (t >> 3) & 63, f = t >> 9;
    int kb = f >> 3, nb = f & 7;
    int rk = kb * 32 + ((l >> 4) << 3) + j;
    int cn = (nb << 4) + (l & 15);
    w1f[t] = f2bf(W1[rk * 128 + cn]);
  } else if (t < 45056) {
    int o = t - 36864;
    int j = o & 7, l = (o >> 3) & 63, f = o >> 9;
    int kb = f >> 2, nb = f & 3;
    int rk = kb * 32 + ((l >> 4) << 3) + j;
    int cn = (nb << 4) + (l & 15);
    w2f[o] = f2bf(W2[rk * 64 + cn]);
  } else if (t < 45184) {
    int j = t - 45056;
    float s = g1[j] * rsqrtf(v1[j] + EPS);
    sc[j] = s;
    sc[128 + j] = (b1[j] - m1[j]) * s + be1[j];
  } else if (t < 45248) {
    int j = t - 45184;
    float s = g2[j] * rsqrtf(v2[j] + EPS);
    sc[256 + j] = s;
    sc[320 + j] = (b2[j] - m2[j]) * s + be2[j];
  }
}

// ---------------- fused main kernel (1024 threads = 16 waves) ----------------
// LDS: [0,73728) W1 frags | [73728,75776) SC | [75776,157696) A region:
//   A-tile [128 x 640B] during L1; then x1 [128x256B] at +0, W2 frags at +32768,
//   l3 f32[256] at +49152
#define LDS_SC_OFF 73728
#define LDS_A_OFF 75776
#define LDS_TOTAL (75776 + 81920)

__global__ __launch_bounds__(1024, 4) void fused_kernel(
    const float* __restrict__ z, const int* __restrict__ ei, const float* __restrict__ ctx,
    const unsigned short* __restrict__ w1f, const unsigned short* __restrict__ w2f,
    const float* __restrict__ sc, const float* __restrict__ w3, const float* __restrict__ b3,
    float* __restrict__ out, int E, int nblk) {
  extern __shared__ char lds[];
  char* W1B = lds;
  float* SC = (float*)(lds + LDS_SC_OFF);
  char* AR = lds + LDS_A_OFF;

  const int tid = threadIdx.x;
  {
    const f32x4* s = (const f32x4*)w1f;
    f32x4* d = (f32x4*)W1B;
#pragma unroll
    for (int i = 0; i < 4; i++) d[i * 1024 + tid] = s[i * 1024 + tid];
    if (tid < 512) d[4096 + tid] = s[4096 + tid];
    if (tid < 128) {
      SC[tid] = sc[tid];
      SC[128 + tid] = sc[128 + tid];
    } else if (tid < 192) {
      int j = tid - 128;
      SC[256 + j] = sc[256 + j];
      SC[320 + j] = sc[320 + j];
      SC[384 + j] = w3[j];
    } else if (tid == 192) {
      SC[448] = b3[0];
    }
  }

  const int lane = tid & 63, wave = tid >> 6;
  const int g = lane >> 4, lq = lane & 15;
  const int wr = wave >> 2, wc = wave & 3;   // L1 grid 4x4: 32 rows x 32 cols per wave
  const int w2r = wave >> 1, w2c = wave & 1; // L2 grid 8x2: 16 rows x 32 cols per wave
  const int sr = tid >> 3, sh = tid & 7;     // staging: 8 threads per edge
  const int grid = gridDim.x;

  // ---- preamble: gather tile t into regs; prefetch ei for tile t+grid ----
  int t = blockIdx.x;
  f32x4 sv0, sv1, dv0, dv1, cv;
  int i0n, i1n;
  {
    int e = (t << 7) + sr;
    int es = e < E ? e : E - 1;
    int a0 = ei[es], a1 = ei[E + es];
    cv = *(const f32x4*)(ctx + (size_t)es * 32 + sh * 4);
    const f32x4* zs = (const f32x4*)(z + ((size_t)a0 * 64 + sh * 8));
    sv0 = zs[0]; sv1 = zs[1];
    const f32x4* zd = (const f32x4*)(z + ((size_t)a1 * 64 + sh * 8));
    dv0 = zd[0]; dv1 = zd[1];
    int tn = t + grid; if (tn >= nblk) tn = t;
    int en = (tn << 7) + sr;
    int esn = en < E ? en : E - 1;
    i0n = ei[esn]; i1n = ei[E + esn];
  }
  __syncthreads();

  for (; t < nblk; t += grid) {
    // ---- write A-tile [128 x 288] bf16 (row stride 640B, XOR-swizzled) from regs ----
    {
      const int rswz = (sr & 7) << 4;
      char* rowp = AR + sr * 640;
      u32x4 ps = {pk2(sv0[0], sv0[1]), pk2(sv0[2], sv0[3]), pk2(sv1[0], sv1[1]), pk2(sv1[2], sv1[3])};
      u32x4 pd = {pk2(dv0[0], dv0[1]), pk2(dv0[2], dv0[3]), pk2(dv1[0], dv1[1]), pk2(dv1[2], dv1[3])};
      u32x4 pp = {pk2(sv0[0] * dv0[0], sv0[1] * dv0[1]), pk2(sv0[2] * dv0[2], sv0[3] * dv0[3]),
                  pk2(sv1[0] * dv1[0], sv1[1] * dv1[1]), pk2(sv1[2] * dv1[2], sv1[3] * dv1[3])};
      u32x4 pa = {pk2(fabsf(sv0[0] - dv0[0]), fabsf(sv0[1] - dv0[1])),
                  pk2(fabsf(sv0[2] - dv0[2]), fabsf(sv0[3] - dv0[3])),
                  pk2(fabsf(sv1[0] - dv1[0]), fabsf(sv1[1] - dv1[1])),
                  pk2(fabsf(sv1[2] - dv1[2]), fabsf(sv1[3] - dv1[3]))};
      u32x2 pc = {pk2(cv[0], cv[1]), pk2(cv[2], cv[3])};
      *(u32x4*)(rowp + ((sh * 16) ^ rswz)) = ps;
      *(u32x4*)(rowp + ((128 + sh * 16) ^ rswz)) = pd;
      *(u32x4*)(rowp + ((256 + sh * 16) ^ rswz)) = pp;
      *(u32x4*)(rowp + ((384 + sh * 16) ^ rswz)) = pa;
      *(u32x2*)(rowp + 512 + ((sh * 8) ^ rswz)) = pc;
    }
    // ---- issue next-tile gathers (T14: latency hides under L1 MFMA) ----
    {
      int tn = t + grid; if (tn >= nblk) tn = t;
      const f32x4* zs = (const f32x4*)(z + ((size_t)i0n * 64 + sh * 8));
      sv0 = zs[0]; sv1 = zs[1];
      const f32x4* zd = (const f32x4*)(z + ((size_t)i1n * 64 + sh * 8));
      dv0 = zd[0]; dv1 = zd[1];
      int en = (tn << 7) + sr;
      int esn = en < E ? en : E - 1;
      cv = *(const f32x4*)(ctx + (size_t)esn * 32 + sh * 4);
      int tn2 = tn + grid; if (tn2 >= nblk) tn2 = tn;
      int en2 = (tn2 << 7) + sr;
      int esn2 = en2 < E ? en2 : E - 1;
      i0n = ei[esn2]; i1n = ei[E + esn2];
    }
    __syncthreads();

    // ---- layer 1: A[128x288] @ W1[288x128]; wave does 2x2 frags ----
    f32x4 acc[2][2];
#pragma unroll
    for (int mf = 0; mf < 2; mf++)
#pragma unroll
      for (int nf = 0; nf < 2; nf++) {
        f32x4 zv = {0.f, 0.f, 0.f, 0.f};
        acc[mf][nf] = zv;
      }
    const bf16x8* W1F = (const bf16x8*)W1B;
#pragma unroll
    for (int kb = 0; kb < 9; kb++) {
      bf16x8 a[2], b[2];
#pragma unroll
      for (int mf = 0; mf < 2; mf++) {
        int row = wr * 32 + mf * 16 + lq;
        a[mf] = *(const bf16x8*)(AR + row * 640 + ((kb * 64 + g * 16) ^ ((row & 7) << 4)));
      }
#pragma unroll
      for (int nf = 0; nf < 2; nf++) b[nf] = W1F[(kb * 8 + wc * 2 + nf) * 64 + lane];
#pragma unroll
      for (int mf = 0; mf < 2; mf++)
#pragma unroll
        for (int nf = 0; nf < 2; nf++)
          acc[mf][nf] = __builtin_amdgcn_mfma_f32_16x16x32_bf16(a[mf], b[nf], acc[mf][nf], 0, 0, 0);
    }
    __syncthreads();

    // ---- stage W2 frags (16 KB) + write x1 (bn+relu, bf16, swizzled) ----
    ((f32x4*)(AR + 32768))[tid] = ((const f32x4*)w2f)[tid];
#pragma unroll
    for (int nf = 0; nf < 2; nf++) {
      const int col = wc * 32 + nf * 16 + lq;
      const float s1v = SC[col], c1v = SC[128 + col];
#pragma unroll
      for (int mf = 0; mf < 2; mf++) {
#pragma unroll
        for (int j = 0; j < 4; j++) {
          int row = wr * 32 + mf * 16 + 4 * g + j;
          float v = fmaxf(acc[mf][nf][j] * s1v + c1v, 0.f);
          *(unsigned short*)(AR + row * 256 + ((col * 2) ^ ((row & 7) << 4))) = f2bf(v);
        }
      }
    }
    __syncthreads();

    // ---- layer 2: x1[128x128] @ W2[128x64]; wave does 1x2 frags ----
    f32x4 acc2[2];
#pragma unroll
    for (int nf = 0; nf < 2; nf++) {
      f32x4 zv = {0.f, 0.f, 0.f, 0.f};
      acc2[nf] = zv;
    }
    const bf16x8* W2F = (const bf16x8*)(AR + 32768);
#pragma unroll
    for (int kb = 0; kb < 4; kb++) {
      int row = w2r * 16 + lq;
      bf16x8 a2 = *(const bf16x8*)(AR + row * 256 + ((kb * 64 + g * 16) ^ ((row & 7) << 4)));
      bf16x8 b2[2];
#pragma unroll
      for (int nf = 0; nf < 2; nf++) b2[nf] = W2F[(kb * 4 + w2c * 2 + nf) * 64 + lane];
#pragma unroll
      for (int nf = 0; nf < 2; nf++)
        acc2[nf] = __builtin_amdgcn_mfma_f32_16x16x32_bf16(a2, b2[nf], acc2[nf], 0, 0, 0);
    }

    // ---- layer 3: bn+relu, dot w3, 16-lane shfl reduce ----
    float* l3 = (float*)(AR + 49152);
    const int colA = w2c * 32 + lq, colB = colA + 16;
    const float s2A = SC[256 + colA], c2A = SC[320 + colA];
    const float s2B = SC[256 + colB], c2B = SC[320 + colB];
    const float w3A = SC[384 + colA], w3B = SC[384 + colB];
#pragma unroll
    for (int j = 0; j < 4; j++) {
      float vA = fmaxf(acc2[0][j] * s2A + c2A, 0.f);
      float vB = fmaxf(acc2[1][j] * s2B + c2B, 0.f);
      float p = vA * w3A + vB * w3B;
      p += __shfl_xor(p, 1);
      p += __shfl_xor(p, 2);
      p += __shfl_xor(p, 4);
      p += __shfl_xor(p, 8);
      if (lq == 0) l3[(w2r * 16 + 4 * g + j) * 2 + w2c] = p;
    }
    __syncthreads();
    if (tid < 128) {
      int e = (t << 7) + tid;
      if (e < E) out[e] = l3[tid * 2] + l3[tid * 2 + 1] + SC[448];
    }
    __syncthreads();
  }
}

extern "C" void kernel_launch(void* const* d_in, const int* in_sizes, int n_in,
                              void* d_out, int out_size, void* d_ws, size_t ws_size,
                              hipStream_t stream) {
  const float* z = (const float*)d_in[0];
  const int* ei = (const int*)d_in[1];
  const float* ctx = (const float*)d_in[2];
  const float* W1 = (const float*)d_in[3];
  const float* b1 = (const float*)d_in[4];
  const float* g1 = (const float*)d_in[5];
  const float* be1 = (const float*)d_in[6];
  const float* m1 = (const float*)d_in[7];
  const float* v1 = (const float*)d_in[8];
  const float* W2 = (const float*)d_in[9];
  const float* b2 = (const float*)d_in[10];
  const float* g2 = (const float*)d_in[11];
  const float* be2 = (const float*)d_in[12];
  const float* m2 = (const float*)d_in[13];
  const float* v2 = (const float*)d_in[14];
  const float* W3 = (const float*)d_in[15];
  const float* b3 = (const float*)d_in[16];
  float* out = (float*)d_out;
  const int E = out_size;

  unsigned short* w1f = (unsigned short*)d_ws;
  unsigned short* w2f = (unsigned short*)((char*)d_ws + 73728);
  float* sc = (float*)((char*)d_ws + 90112);

  prep_kernel<<<177, 256, 0, stream>>>(W1, W2, b1, g1, be1, m1, v1,
                                       b2, g2, be2, m2, v2, w1f, w2f, sc);

  const int nblk = (E + 127) >> 7;
  (void)hipFuncSetAttribute((const void*)fused_kernel,
                            hipFuncAttributeMaxDynamicSharedMemorySize, LDS_TOTAL);
  fused_kernel<<<256, 1024, LDS_TOTAL, stream>>>(z, ei, ctx, w1f, w2f, sc, W3, b3,
                                                 out, E, nblk);
}